// Round 1
// baseline (235.584 us; speedup 1.0000x reference)
//
#include <hip/hip_runtime.h>
#include <hip/hip_bf16.h>

// out[b, c, i, j] = x[b, c, i, j] + pe_flat[g],  g = c*4096 + i*64 + j (flat idx per batch)
// pe_flat is the [H=64, W=64, C=256] pe tensor viewed flat (reference's raw reshape):
//   c2 = g & 255, j2 = (g >> 8) & 63, i2 = (g >> 14) & 63
//   pe = jj*(W0-W2) + ii*(W1-W3) + (W2+W3+b),   jj = j2/63, ii = i2/63
// pe is batch-independent. Grid stride = 2^20 float4 = exactly 4 batches, so each
// thread's within-batch position is loop-invariant -> pe computed once in registers.
//
// R5: single-variable change vs R4 — stores go back through L2 (normal store)
// instead of __builtin_nontemporal_store. Theory: nt stores bypass L2's
// write-burst coalescing; the harness's own fills prove through-L2 writes run
// at 6.8 TB/s, and m13's 6.29 TB/s float4-copy ceiling uses normal stores.
// Loads stay nontemporal (x is stream-once; keeps L2 free for the write stream).

typedef float vf4 __attribute__((ext_vector_type(4)));

#define TOTAL_F4   (1u << 23)        // 32*256*64*64 floats / 4
#define THREADS    256
#define BLOCKS     4096              // 2^20 threads total
#define STRIDE_F4  (1u << 20)        // BLOCKS*THREADS; = 4 batches worth of float4
#define ITERS      8                 // TOTAL_F4 / STRIDE_F4

__global__ __launch_bounds__(THREADS) void pe_add_kernel(
    const float* __restrict__ x,
    const float* __restrict__ Wm,    // [256, 4] row-major
    const float* __restrict__ bias,  // [256]
    float* __restrict__ out)
{
    const unsigned t = blockIdx.x * (unsigned)THREADS + threadIdx.x;   // [0, 2^20)

    // Within-batch position (invariant across iterations).
    const unsigned p  = t & ((1u << 18) - 1u);   // float4 index within a batch
    const unsigned g  = p << 2;                  // element index within a batch
    const unsigned c2 = g & 255u;                // channel of first element (multiple of 4)
    const unsigned j2 = (g >> 8) & 63u;
    const unsigned i2 = (g >> 14) & 63u;

    const float u = (float)j2 * (1.0f / 63.0f);
    const float v = (float)i2 * (1.0f / 63.0f);

    // W rows c2 .. c2+3 : 4 aligned 16B loads (Wm is [256][4]). L1/L2-hot.
    const vf4* Wrows = reinterpret_cast<const vf4*>(Wm);
    const vf4 wa = Wrows[c2 + 0];
    const vf4 wb = Wrows[c2 + 1];
    const vf4 wc = Wrows[c2 + 2];
    const vf4 wd = Wrows[c2 + 3];

    const float pe0 = u * (wa.x - wa.z) + v * (wa.y - wa.w) + (wa.z + wa.w + bias[c2 + 0]);
    const float pe1 = u * (wb.x - wb.z) + v * (wb.y - wb.w) + (wb.z + wb.w + bias[c2 + 1]);
    const float pe2 = u * (wc.x - wc.z) + v * (wc.y - wc.w) + (wc.z + wc.w + bias[c2 + 2]);
    const float pe3 = u * (wd.x - wd.z) + v * (wd.y - wd.w) + (wd.z + wd.w + bias[c2 + 3]);

    const vf4 pe = { pe0, pe1, pe2, pe3 };

    const vf4* xp = reinterpret_cast<const vf4*>(x);
    vf4*       op = reinterpret_cast<vf4*>(out);

    // Phase 1: issue all 8 loads (independent -> 8 outstanding vmem/wave).
    vf4 xv[ITERS];
#pragma unroll
    for (unsigned n = 0; n < ITERS; ++n) {
        const size_t f = (size_t)t + (size_t)n * STRIDE_F4;
        xv[n] = __builtin_nontemporal_load(&xp[f]);
    }

    // Phase 2: add pe, store through L2 (normal store — the 6.3+ TB/s write path).
#pragma unroll
    for (unsigned n = 0; n < ITERS; ++n) {
        const size_t f = (size_t)t + (size_t)n * STRIDE_F4;
        op[f] = xv[n] + pe;
    }
}

extern "C" void kernel_launch(void* const* d_in, const int* in_sizes, int n_in,
                              void* d_out, int out_size, void* d_ws, size_t ws_size,
                              hipStream_t stream) {
    const float* x    = (const float*)d_in[0];  // [32, 256, 64, 64] fp32
    const float* Wm   = (const float*)d_in[1];  // [256, 4] fp32
    const float* bias = (const float*)d_in[2];  // [256] fp32
    float* out = (float*)d_out;                 // [32, 256, 64, 64] fp32

    pe_add_kernel<<<dim3(BLOCKS), dim3(THREADS), 0, stream>>>(x, Wm, bias, out);
}